// Round 11
// baseline (973.838 us; speedup 1.0000x reference)
//
#include <hip/hip_runtime.h>
#include <cstdint>
#include <cstddef>

// Problem constants (B,N,M,D fixed by the reference setup_inputs)
#define BB 8
#define NPTS 2048
#define DIM 64
#define CK 64            // Q cols staged per chunk
#define QC 512           // cols per block (col-split by 4)
#define NC (QC / CK)     // 8 chunks
#define BROWS 128        // P rows per block (4 waves x 32 rows)

typedef _Float16 f16x8 __attribute__((ext_vector_type(8)));
typedef float f32x4 __attribute__((ext_vector_type(4)));

// eps schedule: DIAMETER^2 * 0.25^k down to blur^2 = 0.0025 (9 entries)
static const float EPS_H[9] = {100.0f, 25.0f, 6.25f, 1.5625f, 0.390625f,
                               0.09765625f, 0.0244140625f, 0.006103515625f,
                               0.0025f};
#define LOG2E 1.4426950408889634f
#define LN2 0.6931471805599453f

#if __has_builtin(__builtin_amdgcn_exp2f)
static __device__ __forceinline__ float fexp2(float x) {
  return __builtin_amdgcn_exp2f(x);
}
#else
static __device__ __forceinline__ float fexp2(float x) {
  float r;
  asm("v_exp_f32 %0, %1" : "=v"(r) : "v"(x));
  return r;
}
#endif

static __device__ __forceinline__ f32x4 vmax4(f32x4 a, f32x4 b) {
  f32x4 r;
  #pragma unroll
  for (int i = 0; i < 4; ++i) r[i] = fmaxf(a[i], b[i]);
  return r;
}

static __device__ __forceinline__ f32x4 vexp2_4(f32x4 a) {
  f32x4 r;
  #pragma unroll
  for (int i = 0; i < 4; ++i) r[i] = fexp2(a[i]);
  return r;
}

static __device__ __forceinline__ void gload_lds16(const void* g, void* l) {
  __builtin_amdgcn_global_load_lds(
      (const __attribute__((address_space(1))) void*)g,
      (__attribute__((address_space(3))) void*)l, 16, 0, 0);
}

struct FT {
  const _Float16* P;  // row-side points [B,2048,64]
  const _Float16* Q;  // reduce-side points [B,2048,64]
};
struct MT {
  const float* psq;  // |p|^2 on output rows
  const float* oldf; // averaging input (nullptr = none)
  float* out;        // potential output [B,2048]
  const float* lwn;  // log-weights for NEXT round's hq (Q-side of consumer)
  const float* q2n;  // |q|^2 for NEXT round's hq
  float* hqn;        // hq slice of the consumer task
};

// ---------------- prep kernels ----------------

__global__ __launch_bounds__(256) void norm_weights_k(
    const float* __restrict__ w, float* __restrict__ aout,
    float* __restrict__ logout, int n) {
  int b = blockIdx.x;
  const float* wb = w + (size_t)b * n;
  __shared__ float red[256];
  float s = 0.f;
  for (int i = threadIdx.x; i < n; i += 256) s += wb[i];
  red[threadIdx.x] = s;
  __syncthreads();
  for (int st = 128; st > 0; st >>= 1) {
    if (threadIdx.x < st) red[threadIdx.x] += red[threadIdx.x + st];
    __syncthreads();
  }
  float mass = red[0];
  if (mass == 0.f) mass = 1.f;
  float inv = 1.f / mass;
  for (int i = threadIdx.x; i < n; i += 256) {
    float av = wb[i] * inv;
    aout[(size_t)b * n + i] = av;
    logout[(size_t)b * n + i] = logf(av);
  }
}

// squared norm of each D=64 row + fp16 conversion: one wave per row
__global__ __launch_bounds__(256) void sqnorm_cvt_k(
    const float* __restrict__ X, float* __restrict__ sq,
    _Float16* __restrict__ Xh, int rows) {
  int row = blockIdx.x * 4 + (threadIdx.x >> 6);
  int lane = threadIdx.x & 63;
  if (row >= rows) return;
  float v = X[(size_t)row * DIM + lane];
  Xh[(size_t)row * DIM + lane] = (_Float16)v;
  float s = v * v;
  #pragma unroll
  for (int off = 32; off > 0; off >>= 1) s += __shfl_xor(s, off);
  if (lane == 0) sq[row] = s;
}

// hq init (no potential): hq[t][b][m] = lw*log2e - 0.5*q2*ie2
__global__ __launch_bounds__(256) void init_hq_k(
    const float* __restrict__ la, const float* __restrict__ lb,
    const float* __restrict__ x2, const float* __restrict__ y2,
    float* __restrict__ hq, float ie2) {
  int task = blockIdx.z;
  int idx = blockIdx.x * 256 + threadIdx.x;  // over BB*NPTS
  const float* lw = (task == 1 || task == 2) ? la : lb;
  const float* q2 = (task == 1 || task == 2) ? x2 : y2;
  hq[(size_t)task * BB * NPTS + idx] =
      fmaf(lw[idx], LOG2E, -0.5f * q2[idx] * ie2);
}

// ---------------- fused cost+softmin (2 row-groups, T13 deferred LSE) ------
// Partial over one 512-col quarter: (M,S) per row with invariant
//   S = sum_m 2^{v[r,m] - M},  v = hq[m] + dot(P_r,Q_m)*ie2  (f16 MFMA)
// Block = 4 waves x 32 P-rows (2 row-groups of 16, sharing B-fragments).
// Cols swept in 64-col LDS chunks, double-buffered via global_load_lds,
// counted vmcnt (never 0 in loop), raw s_barriers. hq from precomputed
// global, staged to 2KB LDS. Deferred rescale: M only grows when some
// v > M, and jumps to v+8 (terms bounded by 2^8; pair semantics exact).
// LDS 18KB, VGPR<=64 -> 8 blocks/CU -> 32 waves/CU.
__global__ __launch_bounds__(256, 8) void fused_softmin_k(
    FT t0, FT t1, FT t2, FT t3, const float* __restrict__ hqG,
    float* __restrict__ pmx, float* __restrict__ psm, float ie2) {
  __shared__ float hql[QC];                          // 2 KB
  __shared__ __align__(16) _Float16 qb[2][CK * DIM]; // 2 x 8 KB
  FT T = (blockIdx.z == 0) ? t0
       : (blockIdx.z == 1) ? t1
       : (blockIdx.z == 2) ? t2 : t3;
  const int rowg = blockIdx.x >> 2, qtr = blockIdx.x & 3;
  const int b = blockIdx.y, task = blockIdx.z;
  const int tid = threadIdx.x;

  // stage hq slice for this col-quarter (precomputed on global)
  {
    const float* hqp = hqG + ((size_t)task * BB + b) * NPTS + qtr * QC;
    #pragma unroll
    for (int i = 0; i < QC / 256; ++i)
      hql[i * 256 + tid] = hqp[i * 256 + tid];
  }

  const int lane = tid & 63, wave = tid >> 6;
  const _Float16* Qb = T.Q + ((size_t)b * NPTS + qtr * QC) * DIM;

  // stage chunk -> qb[buf]: linear LDS dest, inverse-swizzled global source
  // (rule #21). granule gid holds Q[m0+gid/8][8 halfs of k-granule
  // (gid%8)^((gid/8)&7)]. 2 global_load_lds per wave per chunk.
  auto stage = [&](int buf, int chunk) {
    int m0 = chunk * CK;
    #pragma unroll
    for (int r = 0; r < 2; ++r) {
      int gbase = r * 256 + wave * 64;
      int gid = gbase + lane;
      int row = gid >> 3;
      int kg = (gid & 7) ^ (row & 7);
      const _Float16* src = Qb + (size_t)(m0 + row) * DIM + kg * 8;
      _Float16* dst = &qb[buf][(size_t)gbase * 8];  // wave-uniform base
      gload_lds16(src, dst);
    }
  };

  const int fr = lane & 15;        // MFMA row/col index within fragment
  const int g0 = lane >> 4;        // k-granule group (0..3)
  const int r0 = rowg * BROWS + wave * 32;
  const _Float16* Pb = T.P + ((size_t)b * NPTS + r0) * DIM;
  f16x8 a00 = *(const f16x8*)(Pb + fr * DIM + g0 * 8);
  f16x8 a01 = *(const f16x8*)(Pb + fr * DIM + g0 * 8 + 32);
  f16x8 a10 = *(const f16x8*)(Pb + (16 + fr) * DIM + g0 * 8);
  f16x8 a11 = *(const f16x8*)(Pb + (16 + fr) * DIM + g0 * 8 + 32);

  f32x4 M0 = {-3.0e38f, -3.0e38f, -3.0e38f, -3.0e38f};
  f32x4 M1 = M0;
  f32x4 S0 = {0.f, 0.f, 0.f, 0.f};
  f32x4 S1 = S0;

  // T13 deferred update: S = sum 2^(x-M); M -> max(M, v+8) only when needed
  auto upd = [&](f32x4 acc, float hs, f32x4& M, f32x4& S) {
    f32x4 v = acc * ie2 + hs;
    bool cfast = (v[0] <= M[0]) & (v[1] <= M[1]) &
                 (v[2] <= M[2]) & (v[3] <= M[3]);
    if (!__all(cfast)) {
      f32x4 nm = vmax4(M, v + 8.f);
      S = S * vexp2_4(M - nm) + vexp2_4(v - nm);
      M = nm;
    } else {
      S += vexp2_4(v - M);
    }
  };

  auto compute = [&](int cur, int mbase) {  // mbase local to the quarter
    const char* qbase = (const char*)&qb[cur][0];
    #pragma unroll
    for (int s = 0; s < 4; ++s) {
      int row = s * 16 + fr;
      int byte0 = row * 128 + ((g0 ^ (row & 7)) << 4);
      int byte1 = row * 128 + (((g0 + 4) ^ (row & 7)) << 4);
      f16x8 b0 = *(const f16x8*)(qbase + byte0);
      f16x8 b1 = *(const f16x8*)(qbase + byte1);
      float hs = hql[mbase + s * 16 + fr];
      f32x4 z = {0.f, 0.f, 0.f, 0.f};
      f32x4 u0 = __builtin_amdgcn_mfma_f32_16x16x32_f16(a00, b0, z, 0, 0, 0);
      f32x4 acc0 = __builtin_amdgcn_mfma_f32_16x16x32_f16(a01, b1, u0, 0, 0, 0);
      f32x4 u1 = __builtin_amdgcn_mfma_f32_16x16x32_f16(a10, b0, z, 0, 0, 0);
      f32x4 acc1 = __builtin_amdgcn_mfma_f32_16x16x32_f16(a11, b1, u1, 0, 0, 0);
      upd(acc0, hs, M0, S0);
      upd(acc1, hs, M1, S1);
    }
  };

  stage(0, 0);
  __syncthreads();  // one full drain: hql visible + chunk-0 staged

  for (int c = 0; c < NC - 1; ++c) {
    int cur = c & 1;
    stage(cur ^ 1, c + 1);  // buffer consumed in iter c-1 (B2 certified)
    // wait my chunk-c loads (2 oldest); keep chunk-(c+1)'s 2 in flight
    asm volatile("s_waitcnt vmcnt(2)" ::: "memory");
    __builtin_amdgcn_sched_barrier(0);
    __builtin_amdgcn_s_barrier();  // B1: chunk c globally staged
    __builtin_amdgcn_sched_barrier(0);
    compute(cur, c * CK);
    __builtin_amdgcn_sched_barrier(0);
    __builtin_amdgcn_s_barrier();  // B2: all waves done reading qb[cur]
    __builtin_amdgcn_sched_barrier(0);
  }
  // peeled last chunk: drain remaining loads (only time vmcnt hits 0)
  asm volatile("s_waitcnt vmcnt(0)" ::: "memory");
  __builtin_amdgcn_sched_barrier(0);
  __builtin_amdgcn_s_barrier();
  __builtin_amdgcn_sched_barrier(0);
  compute((NC - 1) & 1, (NC - 1) * CK);

  // reduce (M,S) pairs over the 16 fr lanes (cols) of each row group
  #pragma unroll
  for (int off = 1; off < 16; off <<= 1) {
    #pragma unroll
    for (int q = 0; q < 4; ++q) {
      {
        float om = __shfl_xor(M0[q], off);
        float os = __shfl_xor(S0[q], off);
        float nm = fmaxf(M0[q], om);
        S0[q] = S0[q] * fexp2(M0[q] - nm) + os * fexp2(om - nm);
        M0[q] = nm;
      }
      {
        float om = __shfl_xor(M1[q], off);
        float os = __shfl_xor(S1[q], off);
        float nm = fmaxf(M1[q], om);
        S1[q] = S1[q] * fexp2(M1[q] - nm) + os * fexp2(om - nm);
        M1[q] = nm;
      }
    }
  }
  if (fr == 0) {
    #pragma unroll
    for (int q = 0; q < 4; ++q) {
      // layout [task][b][qtr][row]
      size_t pbase = (((size_t)task * BB + b) * 4 + qtr) * NPTS;
      int ra = r0 + g0 * 4 + q;
      pmx[pbase + ra] = M0[q];
      psm[pbase + ra] = S0[q];
      int rb = ra + 16;
      pmx[pbase + rb] = M1[q];
      psm[pbase + rb] = S1[q];
    }
  }
}

// ---------------- merge quarters + epilogue + next-round hq ----------------
__global__ __launch_bounds__(256) void merge_k(
    const float* __restrict__ pmx, const float* __restrict__ psm,
    MT m0, MT m1, MT m2, MT m3, float nel, float ie2n, int whq) {
  int task = blockIdx.z;
  MT M = (task == 0) ? m0 : (task == 1) ? m1 : (task == 2) ? m2 : m3;
  int idx = blockIdx.x * 256 + threadIdx.x;  // over BB*NPTS
  int b = idx >> 11;                          // NPTS = 2048
  int r = idx & 2047;
  size_t pb = (((size_t)task * BB + b) * 4) * NPTS + r;
  float ma[4], sa[4];
  #pragma unroll
  for (int k = 0; k < 4; ++k) {
    ma[k] = pmx[pb + (size_t)k * NPTS];
    sa[k] = psm[pb + (size_t)k * NPTS];
  }
  float nm = fmaxf(fmaxf(ma[0], ma[1]), fmaxf(ma[2], ma[3]));
  float ss = 0.f;
  #pragma unroll
  for (int k = 0; k < 4; ++k) ss += sa[k] * fexp2(ma[k] - nm);
  float f = nel * (__log2f(ss) + nm) + 0.5f * M.psq[idx];
  if (M.oldf) f = 0.5f * (M.oldf[idx] + f);
  M.out[idx] = f;
  if (whq) {
    float h = fmaf(f, ie2n, fmaf(M.lwn[idx], LOG2E, -0.5f * M.q2n[idx] * ie2n));
    M.hqn[idx] = h;
  }
}

// ---------------- loss epilogue (two-stage) ----------------
__global__ __launch_bounds__(256) void loss_part_k(
    const float* __restrict__ aW, const float* __restrict__ f_fin,
    const float* __restrict__ f_aa, const float* __restrict__ bW,
    const float* __restrict__ g_fin, const float* __restrict__ g_bb,
    float* __restrict__ part) {
  __shared__ float red[256];
  int i0 = blockIdx.x * 256 + threadIdx.x;
  float s = 0.f;
  for (int i = i0; i < BB * NPTS; i += 64 * 256)
    s += aW[i] * (f_fin[i] - f_aa[i]) + bW[i] * (g_fin[i] - g_bb[i]);
  red[threadIdx.x] = s;
  __syncthreads();
  for (int st = 128; st > 0; st >>= 1) {
    if (threadIdx.x < st) red[threadIdx.x] += red[threadIdx.x + st];
    __syncthreads();
  }
  if (threadIdx.x == 0) part[blockIdx.x] = red[0];
}

__global__ __launch_bounds__(64) void loss_fin_k(const float* __restrict__ part,
                                                 float* __restrict__ out) {
  float s = part[threadIdx.x];
  #pragma unroll
  for (int off = 32; off > 0; off >>= 1) s += __shfl_xor(s, off);
  if (threadIdx.x == 0) out[0] = s * (1.f / BB);
}

__global__ void write_val_k(float* out, float v) { out[0] = v; }

// ---------------- host ----------------

extern "C" void kernel_launch(void* const* d_in, const int* in_sizes, int n_in,
                              void* d_out, int out_size, void* d_ws,
                              size_t ws_size, hipStream_t stream) {
  (void)in_sizes; (void)n_in; (void)out_size;
  const float* X = (const float*)d_in[0];   // [B,N,D]
  const float* Y = (const float*)d_in[1];   // [B,M,D]
  const float* W1 = (const float*)d_in[2];  // [B,N]
  const float* W2 = (const float*)d_in[3];  // [B,M]
  float* out = (float*)d_out;

  char* base = (char*)d_ws;
  size_t off = 0;
  auto alloc_b = [&](size_t bytes) {
    void* r = base + off;
    off += (bytes + 255) & ~(size_t)255;
    return r;
  };
  const size_t nP = (size_t)BB * NPTS;
  _Float16* Xh = (_Float16*)alloc_b(nP * DIM * 2);
  _Float16* Yh = (_Float16*)alloc_b(nP * DIM * 2);
  float* x2 = (float*)alloc_b(nP * 4);
  float* y2 = (float*)alloc_b(nP * 4);
  float* aW = (float*)alloc_b(nP * 4);
  float* bW = (float*)alloc_b(nP * 4);
  float* la = (float*)alloc_b(nP * 4);
  float* lb = (float*)alloc_b(nP * 4);
  float* fba[2] = {(float*)alloc_b(nP * 4), (float*)alloc_b(nP * 4)};
  float* gab[2] = {(float*)alloc_b(nP * 4), (float*)alloc_b(nP * 4)};
  float* faa[2] = {(float*)alloc_b(nP * 4), (float*)alloc_b(nP * 4)};
  float* gbb[2] = {(float*)alloc_b(nP * 4), (float*)alloc_b(nP * 4)};
  float* hq = (float*)alloc_b(4 * nP * 4);
  float* pmx = (float*)alloc_b(4 * nP * 4 * 4);
  float* psm = (float*)alloc_b(4 * nP * 4 * 4);
  float* part = (float*)alloc_b(64 * 4);
  if (ws_size < off) {
    write_val_k<<<1, 1, 0, stream>>>(out, -(float)(ws_size >> 20));
    return;
  }

  // prep
  norm_weights_k<<<BB, 256, 0, stream>>>(W1, aW, la, NPTS);
  norm_weights_k<<<BB, 256, 0, stream>>>(W2, bW, lb, NPTS);
  sqnorm_cvt_k<<<BB * NPTS / 4, 256, 0, stream>>>(X, x2, Xh, BB * NPTS);
  sqnorm_cvt_k<<<BB * NPTS / 4, 256, 0, stream>>>(Y, y2, Yh, BB * NPTS);

  dim3 fg(64, BB, 4);        // (rowg*4+qtr, b, task)
  dim3 mg(BB * NPTS / 256, 1, 4);

  FT t0{Xh, Yh}, t1{Yh, Xh}, t2{Xh, Xh}, t3{Yh, Yh};
  float* hq0 = hq;                 // task0 slice (f_ba: pot=gab)
  float* hq1 = hq + 1 * nP;        // task1 (g_ab: pot=fba)
  float* hq2 = hq + 2 * nP;        // task2 (f_aa: pot=faa)
  float* hq3 = hq + 3 * nP;        // task3 (g_bb: pot=gbb)

  auto fused = [&](float eps) {
    fused_softmin_k<<<fg, 256, 0, stream>>>(t0, t1, t2, t3, hq, pmx, psm,
                                            LOG2E / eps);
  };
  // merge for all 4 tasks; out-task t feeds hq of consumer: t0->hq1, t1->hq0,
  // t2->hq2, t3->hq3 (lw/q2 of the consumer's Q side).
  auto merge = [&](float eps, float ie2n, int whq, const float* oF,
                   float* nF, const float* oG, float* nG, const float* oA,
                   float* nA, const float* oB, float* nB) {
    float nel = -eps * LN2;
    MT M0{x2, oF, nF, la, x2, hq1};
    MT M1{y2, oG, nG, lb, y2, hq0};
    MT M2{x2, oA, nA, la, x2, hq2};
    MT M3{y2, oB, nB, lb, y2, hq3};
    merge_k<<<mg, 256, 0, stream>>>(pmx, psm, M0, M1, M2, M3, nel, ie2n, whq);
  };

  // hq for the init round (no potential)
  init_hq_k<<<mg, 256, 0, stream>>>(la, lb, x2, y2, hq, LOG2E / EPS_H[0]);

  // init round at eps0 (no averaging); next round is loop it=0 at eps0
  fused(EPS_H[0]);
  merge(EPS_H[0], LOG2E / EPS_H[0], 1, nullptr, fba[0], nullptr, gab[0],
        nullptr, faa[0], nullptr, gbb[0]);

  // annealing loop: averaged updates, double-buffered
  int cur = 0;
  for (int it = 0; it < 9; ++it) {
    int nxt = cur ^ 1;
    float epsn = EPS_H[it < 8 ? it + 1 : 8];  // it=8 feeds final extrapolation
    fused(EPS_H[it]);
    merge(EPS_H[it], LOG2E / epsn, 1, fba[cur], fba[nxt], gab[cur], gab[nxt],
          faa[cur], faa[nxt], gbb[cur], gbb[nxt]);
    cur = nxt;
  }

  // final extrapolation at eps target (no averaging, no hq write)
  {
    int nxt = cur ^ 1;
    fused(EPS_H[8]);
    merge(EPS_H[8], 0.f, 0, nullptr, fba[nxt], nullptr, gab[nxt], nullptr,
          faa[nxt], nullptr, gbb[nxt]);
    loss_part_k<<<64, 256, 0, stream>>>(aW, fba[nxt], faa[nxt], bW, gab[nxt],
                                        gbb[nxt], part);
    loss_fin_k<<<1, 64, 0, stream>>>(part, out);
  }
}

// Round 12
// 782.110 us; speedup vs baseline: 1.2451x; 1.2451x over previous
//
#include <hip/hip_runtime.h>
#include <cstdint>
#include <cstddef>

// Problem constants (B,N,M,D fixed by the reference setup_inputs)
#define BB 8
#define NPTS 2048
#define DIM 64
#define CK 64            // Q cols staged per chunk
#define QC 512           // cols per block (col-split by 4)
#define NC (QC / CK)     // 8 chunks
#define BROWS 128        // P rows per block (4 waves x 32 rows)

typedef _Float16 f16x8 __attribute__((ext_vector_type(8)));
typedef float f32x4 __attribute__((ext_vector_type(4)));

// eps schedule: DIAMETER^2 * 0.25^k down to blur^2 = 0.0025 (9 entries)
static const float EPS_H[9] = {100.0f, 25.0f, 6.25f, 1.5625f, 0.390625f,
                               0.09765625f, 0.0244140625f, 0.006103515625f,
                               0.0025f};
#define LOG2E 1.4426950408889634f
#define LN2 0.6931471805599453f

#if __has_builtin(__builtin_amdgcn_exp2f)
static __device__ __forceinline__ float fexp2(float x) {
  return __builtin_amdgcn_exp2f(x);
}
#else
static __device__ __forceinline__ float fexp2(float x) {
  float r;
  asm("v_exp_f32 %0, %1" : "=v"(r) : "v"(x));
  return r;
}
#endif

static __device__ __forceinline__ f32x4 vmax4(f32x4 a, f32x4 b) {
  f32x4 r;
  #pragma unroll
  for (int i = 0; i < 4; ++i) r[i] = fmaxf(a[i], b[i]);
  return r;
}

static __device__ __forceinline__ f32x4 vexp2_4(f32x4 a) {
  f32x4 r;
  #pragma unroll
  for (int i = 0; i < 4; ++i) r[i] = fexp2(a[i]);
  return r;
}

static __device__ __forceinline__ void gload_lds16(const void* g, void* l) {
  __builtin_amdgcn_global_load_lds(
      (const __attribute__((address_space(1))) void*)g,
      (__attribute__((address_space(3))) void*)l, 16, 0, 0);
}

struct FT {
  const _Float16* P;  // row-side points [B,2048,64]
  const _Float16* Q;  // reduce-side points [B,2048,64]
};
struct MT {
  const float* psq;  // |p|^2 on output rows
  const float* oldf; // averaging input (nullptr = none)
  float* out;        // potential output [B,2048]
  const float* lwn;  // log-weights for NEXT round's hq (Q-side of consumer)
  const float* q2n;  // |q|^2 for NEXT round's hq
  float* hqn;        // hq slice of the consumer task
};

// ---------------- prep kernels ----------------

__global__ __launch_bounds__(256) void norm_weights_k(
    const float* __restrict__ w, float* __restrict__ aout,
    float* __restrict__ logout, int n) {
  int b = blockIdx.x;
  const float* wb = w + (size_t)b * n;
  __shared__ float red[256];
  float s = 0.f;
  for (int i = threadIdx.x; i < n; i += 256) s += wb[i];
  red[threadIdx.x] = s;
  __syncthreads();
  for (int st = 128; st > 0; st >>= 1) {
    if (threadIdx.x < st) red[threadIdx.x] += red[threadIdx.x + st];
    __syncthreads();
  }
  float mass = red[0];
  if (mass == 0.f) mass = 1.f;
  float inv = 1.f / mass;
  for (int i = threadIdx.x; i < n; i += 256) {
    float av = wb[i] * inv;
    aout[(size_t)b * n + i] = av;
    logout[(size_t)b * n + i] = logf(av);
  }
}

// squared norm of each D=64 row + fp16 conversion: one wave per row
__global__ __launch_bounds__(256) void sqnorm_cvt_k(
    const float* __restrict__ X, float* __restrict__ sq,
    _Float16* __restrict__ Xh, int rows) {
  int row = blockIdx.x * 4 + (threadIdx.x >> 6);
  int lane = threadIdx.x & 63;
  if (row >= rows) return;
  float v = X[(size_t)row * DIM + lane];
  Xh[(size_t)row * DIM + lane] = (_Float16)v;
  float s = v * v;
  #pragma unroll
  for (int off = 32; off > 0; off >>= 1) s += __shfl_xor(s, off);
  if (lane == 0) sq[row] = s;
}

// hq init (no potential): hq[t][b][m] = lw*log2e - 0.5*q2*ie2
__global__ __launch_bounds__(256) void init_hq_k(
    const float* __restrict__ la, const float* __restrict__ lb,
    const float* __restrict__ x2, const float* __restrict__ y2,
    float* __restrict__ hq, float ie2) {
  int task = blockIdx.z;
  int idx = blockIdx.x * 256 + threadIdx.x;  // over BB*NPTS
  const float* lw = (task == 1 || task == 2) ? la : lb;
  const float* q2 = (task == 1 || task == 2) ? x2 : y2;
  hq[(size_t)task * BB * NPTS + idx] =
      fmaf(lw[idx], LOG2E, -0.5f * q2[idx] * ie2);
}

// ---------------- fused cost+softmin (2 row-groups, amortized LSE) ---------
// Partial over one 512-col quarter: (M,S) per row with
//   v[r,m] = hq[m] + dot(P_r,Q_m)*ie2  (f16 MFMA 16x16x32, fp32 acc)
// Block = 4 waves x 32 P-rows (2 row-groups of 16, SHARING each staged
// B-fragment -> LDS-read bytes per entry halved vs 1 row-group).
// Cols swept in 64-col LDS chunks, double-buffered via global_load_lds,
// counted vmcnt (never 0 in loop), raw s_barriers. hq from precomputed
// global, staged to 2KB LDS. LSE: UNCONDITIONAL amortized rescale per
// 32-col group (R10 scheme — no branch; T13 guard refuted in R11).
// LDS 18KB, VGPR<=64 -> 8 blocks/CU -> 32 waves/CU.
__global__ __launch_bounds__(256, 8) void fused_softmin_k(
    FT t0, FT t1, FT t2, FT t3, const float* __restrict__ hqG,
    float* __restrict__ pmx, float* __restrict__ psm, float ie2) {
  __shared__ float hql[QC];                          // 2 KB
  __shared__ __align__(16) _Float16 qb[2][CK * DIM]; // 2 x 8 KB
  FT T = (blockIdx.z == 0) ? t0
       : (blockIdx.z == 1) ? t1
       : (blockIdx.z == 2) ? t2 : t3;
  const int rowg = blockIdx.x >> 2, qtr = blockIdx.x & 3;
  const int b = blockIdx.y, task = blockIdx.z;
  const int tid = threadIdx.x;

  // stage hq slice for this col-quarter (precomputed on global)
  {
    const float* hqp = hqG + ((size_t)task * BB + b) * NPTS + qtr * QC;
    #pragma unroll
    for (int i = 0; i < QC / 256; ++i)
      hql[i * 256 + tid] = hqp[i * 256 + tid];
  }

  const int lane = tid & 63, wave = tid >> 6;
  const _Float16* Qb = T.Q + ((size_t)b * NPTS + qtr * QC) * DIM;

  // stage chunk -> qb[buf]: linear LDS dest, inverse-swizzled global source
  // (rule #21). granule gid holds Q[m0+gid/8][8 halfs of k-granule
  // (gid%8)^((gid/8)&7)]. 2 global_load_lds per wave per chunk.
  auto stage = [&](int buf, int chunk) {
    int m0 = chunk * CK;
    #pragma unroll
    for (int r = 0; r < 2; ++r) {
      int gbase = r * 256 + wave * 64;
      int gid = gbase + lane;
      int row = gid >> 3;
      int kg = (gid & 7) ^ (row & 7);
      const _Float16* src = Qb + (size_t)(m0 + row) * DIM + kg * 8;
      _Float16* dst = &qb[buf][(size_t)gbase * 8];  // wave-uniform base
      gload_lds16(src, dst);
    }
  };

  const int fr = lane & 15;        // MFMA row/col index within fragment
  const int g0 = lane >> 4;        // k-granule group (0..3)
  const int r0 = rowg * BROWS + wave * 32;
  const _Float16* Pb = T.P + ((size_t)b * NPTS + r0) * DIM;
  f16x8 a00 = *(const f16x8*)(Pb + fr * DIM + g0 * 8);
  f16x8 a01 = *(const f16x8*)(Pb + fr * DIM + g0 * 8 + 32);
  f16x8 a10 = *(const f16x8*)(Pb + (16 + fr) * DIM + g0 * 8);
  f16x8 a11 = *(const f16x8*)(Pb + (16 + fr) * DIM + g0 * 8 + 32);

  f32x4 M0 = {-3.0e38f, -3.0e38f, -3.0e38f, -3.0e38f};
  f32x4 M1 = M0;
  f32x4 S0 = {0.f, 0.f, 0.f, 0.f};
  f32x4 S1 = S0;

  auto compute = [&](int cur, int mbase) {  // mbase local to the quarter
    const char* qbase = (const char*)&qb[cur][0];
    #pragma unroll
    for (int sh = 0; sh < 2; ++sh) {
      f32x4 acc00, acc01, acc10, acc11;  // [rg][s2], static names (rule #20)
      float hs0, hs1;
      {
        int row = (sh * 2) * 16 + fr;
        int byte0 = row * 128 + ((g0 ^ (row & 7)) << 4);
        int byte1 = row * 128 + (((g0 + 4) ^ (row & 7)) << 4);
        f16x8 b0 = *(const f16x8*)(qbase + byte0);
        f16x8 b1 = *(const f16x8*)(qbase + byte1);
        hs0 = hql[mbase + (sh * 2) * 16 + fr];
        f32x4 z = {0.f, 0.f, 0.f, 0.f};
        f32x4 u0 = __builtin_amdgcn_mfma_f32_16x16x32_f16(a00, b0, z, 0, 0, 0);
        acc00 = __builtin_amdgcn_mfma_f32_16x16x32_f16(a01, b1, u0, 0, 0, 0);
        f32x4 u1 = __builtin_amdgcn_mfma_f32_16x16x32_f16(a10, b0, z, 0, 0, 0);
        acc10 = __builtin_amdgcn_mfma_f32_16x16x32_f16(a11, b1, u1, 0, 0, 0);
      }
      {
        int row = (sh * 2 + 1) * 16 + fr;
        int byte0 = row * 128 + ((g0 ^ (row & 7)) << 4);
        int byte1 = row * 128 + (((g0 + 4) ^ (row & 7)) << 4);
        f16x8 b0 = *(const f16x8*)(qbase + byte0);
        f16x8 b1 = *(const f16x8*)(qbase + byte1);
        hs1 = hql[mbase + (sh * 2 + 1) * 16 + fr];
        f32x4 z = {0.f, 0.f, 0.f, 0.f};
        f32x4 u0 = __builtin_amdgcn_mfma_f32_16x16x32_f16(a00, b0, z, 0, 0, 0);
        acc01 = __builtin_amdgcn_mfma_f32_16x16x32_f16(a01, b1, u0, 0, 0, 0);
        f32x4 u1 = __builtin_amdgcn_mfma_f32_16x16x32_f16(a10, b0, z, 0, 0, 0);
        acc11 = __builtin_amdgcn_mfma_f32_16x16x32_f16(a11, b1, u1, 0, 0, 0);
      }
      // amortized LSE over this 32-col group, row-group 0
      {
        f32x4 v0 = acc00 * ie2 + hs0;
        f32x4 v1 = acc01 * ie2 + hs1;
        f32x4 cm = vmax4(M0, vmax4(v0, v1));
        S0 = S0 * vexp2_4(M0 - cm) + vexp2_4(v0 - cm) + vexp2_4(v1 - cm);
        M0 = cm;
      }
      // row-group 1
      {
        f32x4 v0 = acc10 * ie2 + hs0;
        f32x4 v1 = acc11 * ie2 + hs1;
        f32x4 cm = vmax4(M1, vmax4(v0, v1));
        S1 = S1 * vexp2_4(M1 - cm) + vexp2_4(v0 - cm) + vexp2_4(v1 - cm);
        M1 = cm;
      }
    }
  };

  stage(0, 0);
  __syncthreads();  // one full drain: hql visible + chunk-0 staged

  for (int c = 0; c < NC - 1; ++c) {
    int cur = c & 1;
    stage(cur ^ 1, c + 1);  // buffer consumed in iter c-1 (B2 certified)
    // wait my chunk-c loads (2 oldest); keep chunk-(c+1)'s 2 in flight
    asm volatile("s_waitcnt vmcnt(2)" ::: "memory");
    __builtin_amdgcn_sched_barrier(0);
    __builtin_amdgcn_s_barrier();  // B1: chunk c globally staged
    __builtin_amdgcn_sched_barrier(0);
    compute(cur, c * CK);
    __builtin_amdgcn_sched_barrier(0);
    __builtin_amdgcn_s_barrier();  // B2: all waves done reading qb[cur]
    __builtin_amdgcn_sched_barrier(0);
  }
  // peeled last chunk: drain remaining loads (only time vmcnt hits 0)
  asm volatile("s_waitcnt vmcnt(0)" ::: "memory");
  __builtin_amdgcn_sched_barrier(0);
  __builtin_amdgcn_s_barrier();
  __builtin_amdgcn_sched_barrier(0);
  compute((NC - 1) & 1, (NC - 1) * CK);

  // reduce (M,S) pairs over the 16 fr lanes (cols) of each row group
  #pragma unroll
  for (int off = 1; off < 16; off <<= 1) {
    #pragma unroll
    for (int q = 0; q < 4; ++q) {
      {
        float om = __shfl_xor(M0[q], off);
        float os = __shfl_xor(S0[q], off);
        float nm = fmaxf(M0[q], om);
        S0[q] = S0[q] * fexp2(M0[q] - nm) + os * fexp2(om - nm);
        M0[q] = nm;
      }
      {
        float om = __shfl_xor(M1[q], off);
        float os = __shfl_xor(S1[q], off);
        float nm = fmaxf(M1[q], om);
        S1[q] = S1[q] * fexp2(M1[q] - nm) + os * fexp2(om - nm);
        M1[q] = nm;
      }
    }
  }
  if (fr == 0) {
    #pragma unroll
    for (int q = 0; q < 4; ++q) {
      // layout [task][b][qtr][row]
      size_t pbase = (((size_t)task * BB + b) * 4 + qtr) * NPTS;
      int ra = r0 + g0 * 4 + q;
      pmx[pbase + ra] = M0[q];
      psm[pbase + ra] = S0[q];
      int rb = ra + 16;
      pmx[pbase + rb] = M1[q];
      psm[pbase + rb] = S1[q];
    }
  }
}

// ---------------- merge quarters + epilogue + next-round hq ----------------
__global__ __launch_bounds__(256) void merge_k(
    const float* __restrict__ pmx, const float* __restrict__ psm,
    MT m0, MT m1, MT m2, MT m3, float nel, float ie2n, int whq) {
  int task = blockIdx.z;
  MT M = (task == 0) ? m0 : (task == 1) ? m1 : (task == 2) ? m2 : m3;
  int idx = blockIdx.x * 256 + threadIdx.x;  // over BB*NPTS
  int b = idx >> 11;                          // NPTS = 2048
  int r = idx & 2047;
  size_t pb = (((size_t)task * BB + b) * 4) * NPTS + r;
  float ma[4], sa[4];
  #pragma unroll
  for (int k = 0; k < 4; ++k) {
    ma[k] = pmx[pb + (size_t)k * NPTS];
    sa[k] = psm[pb + (size_t)k * NPTS];
  }
  float nm = fmaxf(fmaxf(ma[0], ma[1]), fmaxf(ma[2], ma[3]));
  float ss = 0.f;
  #pragma unroll
  for (int k = 0; k < 4; ++k) ss += sa[k] * fexp2(ma[k] - nm);
  float f = nel * (__log2f(ss) + nm) + 0.5f * M.psq[idx];
  if (M.oldf) f = 0.5f * (M.oldf[idx] + f);
  M.out[idx] = f;
  if (whq) {
    float h = fmaf(f, ie2n, fmaf(M.lwn[idx], LOG2E, -0.5f * M.q2n[idx] * ie2n));
    M.hqn[idx] = h;
  }
}

// ---------------- loss epilogue (two-stage) ----------------
__global__ __launch_bounds__(256) void loss_part_k(
    const float* __restrict__ aW, const float* __restrict__ f_fin,
    const float* __restrict__ f_aa, const float* __restrict__ bW,
    const float* __restrict__ g_fin, const float* __restrict__ g_bb,
    float* __restrict__ part) {
  __shared__ float red[256];
  int i0 = blockIdx.x * 256 + threadIdx.x;
  float s = 0.f;
  for (int i = i0; i < BB * NPTS; i += 64 * 256)
    s += aW[i] * (f_fin[i] - f_aa[i]) + bW[i] * (g_fin[i] - g_bb[i]);
  red[threadIdx.x] = s;
  __syncthreads();
  for (int st = 128; st > 0; st >>= 1) {
    if (threadIdx.x < st) red[threadIdx.x] += red[threadIdx.x + st];
    __syncthreads();
  }
  if (threadIdx.x == 0) part[blockIdx.x] = red[0];
}

__global__ __launch_bounds__(64) void loss_fin_k(const float* __restrict__ part,
                                                 float* __restrict__ out) {
  float s = part[threadIdx.x];
  #pragma unroll
  for (int off = 32; off > 0; off >>= 1) s += __shfl_xor(s, off);
  if (threadIdx.x == 0) out[0] = s * (1.f / BB);
}

__global__ void write_val_k(float* out, float v) { out[0] = v; }

// ---------------- host ----------------

extern "C" void kernel_launch(void* const* d_in, const int* in_sizes, int n_in,
                              void* d_out, int out_size, void* d_ws,
                              size_t ws_size, hipStream_t stream) {
  (void)in_sizes; (void)n_in; (void)out_size;
  const float* X = (const float*)d_in[0];   // [B,N,D]
  const float* Y = (const float*)d_in[1];   // [B,M,D]
  const float* W1 = (const float*)d_in[2];  // [B,N]
  const float* W2 = (const float*)d_in[3];  // [B,M]
  float* out = (float*)d_out;

  char* base = (char*)d_ws;
  size_t off = 0;
  auto alloc_b = [&](size_t bytes) {
    void* r = base + off;
    off += (bytes + 255) & ~(size_t)255;
    return r;
  };
  const size_t nP = (size_t)BB * NPTS;
  _Float16* Xh = (_Float16*)alloc_b(nP * DIM * 2);
  _Float16* Yh = (_Float16*)alloc_b(nP * DIM * 2);
  float* x2 = (float*)alloc_b(nP * 4);
  float* y2 = (float*)alloc_b(nP * 4);
  float* aW = (float*)alloc_b(nP * 4);
  float* bW = (float*)alloc_b(nP * 4);
  float* la = (float*)alloc_b(nP * 4);
  float* lb = (float*)alloc_b(nP * 4);
  float* fba[2] = {(float*)alloc_b(nP * 4), (float*)alloc_b(nP * 4)};
  float* gab[2] = {(float*)alloc_b(nP * 4), (float*)alloc_b(nP * 4)};
  float* faa[2] = {(float*)alloc_b(nP * 4), (float*)alloc_b(nP * 4)};
  float* gbb[2] = {(float*)alloc_b(nP * 4), (float*)alloc_b(nP * 4)};
  float* hq = (float*)alloc_b(4 * nP * 4);
  float* pmx = (float*)alloc_b(4 * nP * 4 * 4);
  float* psm = (float*)alloc_b(4 * nP * 4 * 4);
  float* part = (float*)alloc_b(64 * 4);
  if (ws_size < off) {
    write_val_k<<<1, 1, 0, stream>>>(out, -(float)(ws_size >> 20));
    return;
  }

  // prep
  norm_weights_k<<<BB, 256, 0, stream>>>(W1, aW, la, NPTS);
  norm_weights_k<<<BB, 256, 0, stream>>>(W2, bW, lb, NPTS);
  sqnorm_cvt_k<<<BB * NPTS / 4, 256, 0, stream>>>(X, x2, Xh, BB * NPTS);
  sqnorm_cvt_k<<<BB * NPTS / 4, 256, 0, stream>>>(Y, y2, Yh, BB * NPTS);

  dim3 fg(64, BB, 4);        // (rowg*4+qtr, b, task)
  dim3 mg(BB * NPTS / 256, 1, 4);

  FT t0{Xh, Yh}, t1{Yh, Xh}, t2{Xh, Xh}, t3{Yh, Yh};
  float* hq0 = hq;                 // task0 slice (f_ba: pot=gab)
  float* hq1 = hq + 1 * nP;        // task1 (g_ab: pot=fba)
  float* hq2 = hq + 2 * nP;        // task2 (f_aa: pot=faa)
  float* hq3 = hq + 3 * nP;        // task3 (g_bb: pot=gbb)

  auto fused = [&](float eps) {
    fused_softmin_k<<<fg, 256, 0, stream>>>(t0, t1, t2, t3, hq, pmx, psm,
                                            LOG2E / eps);
  };
  // merge for all 4 tasks; out-task t feeds hq of consumer: t0->hq1, t1->hq0,
  // t2->hq2, t3->hq3 (lw/q2 of the consumer's Q side).
  auto merge = [&](float eps, float ie2n, int whq, const float* oF,
                   float* nF, const float* oG, float* nG, const float* oA,
                   float* nA, const float* oB, float* nB) {
    float nel = -eps * LN2;
    MT M0{x2, oF, nF, la, x2, hq1};
    MT M1{y2, oG, nG, lb, y2, hq0};
    MT M2{x2, oA, nA, la, x2, hq2};
    MT M3{y2, oB, nB, lb, y2, hq3};
    merge_k<<<mg, 256, 0, stream>>>(pmx, psm, M0, M1, M2, M3, nel, ie2n, whq);
  };

  // hq for the init round (no potential)
  init_hq_k<<<mg, 256, 0, stream>>>(la, lb, x2, y2, hq, LOG2E / EPS_H[0]);

  // init round at eps0 (no averaging); next round is loop it=0 at eps0
  fused(EPS_H[0]);
  merge(EPS_H[0], LOG2E / EPS_H[0], 1, nullptr, fba[0], nullptr, gab[0],
        nullptr, faa[0], nullptr, gbb[0]);

  // annealing loop: averaged updates, double-buffered
  int cur = 0;
  for (int it = 0; it < 9; ++it) {
    int nxt = cur ^ 1;
    float epsn = EPS_H[it < 8 ? it + 1 : 8];  // it=8 feeds final extrapolation
    fused(EPS_H[it]);
    merge(EPS_H[it], LOG2E / epsn, 1, fba[cur], fba[nxt], gab[cur], gab[nxt],
          faa[cur], faa[nxt], gbb[cur], gbb[nxt]);
    cur = nxt;
  }

  // final extrapolation at eps target (no averaging, no hq write)
  {
    int nxt = cur ^ 1;
    fused(EPS_H[8]);
    merge(EPS_H[8], 0.f, 0, nullptr, fba[nxt], nullptr, gab[nxt], nullptr,
          faa[nxt], nullptr, gbb[nxt]);
    loss_part_k<<<64, 256, 0, stream>>>(aW, fba[nxt], faa[nxt], bW, gab[nxt],
                                        gbb[nxt], part);
    loss_fin_k<<<1, 64, 0, stream>>>(part, out);
  }
}

// Round 14
// 476.586 us; speedup vs baseline: 2.0434x; 1.6411x over previous
//
#include <hip/hip_runtime.h>
#include <cstdint>
#include <cstddef>

// Problem constants (B,N,M,D fixed by the reference setup_inputs)
#define BB 8
#define NPTS 2048
#define DIM 64
#define CK 64            // Q cols staged per chunk
#define QC 512           // cols per block (col-split by 4)
#define NC (QC / CK)     // 8 chunks
#define BROWS 128        // P rows per block (4 waves x 32 rows)

typedef _Float16 f16x8 __attribute__((ext_vector_type(8)));
typedef float f32x4 __attribute__((ext_vector_type(4)));

// eps schedule: DIAMETER^2 * 0.25^k down to blur^2 = 0.0025 (9 entries)
static const float EPS_H[9] = {100.0f, 25.0f, 6.25f, 1.5625f, 0.390625f,
                               0.09765625f, 0.0244140625f, 0.006103515625f,
                               0.0025f};
#define LOG2E 1.4426950408889634f
#define LN2 0.6931471805599453f

#if __has_builtin(__builtin_amdgcn_exp2f)
static __device__ __forceinline__ float fexp2(float x) {
  return __builtin_amdgcn_exp2f(x);
}
#else
static __device__ __forceinline__ float fexp2(float x) {
  float r;
  asm("v_exp_f32 %0, %1" : "=v"(r) : "v"(x));
  return r;
}
#endif

static __device__ __forceinline__ f32x4 vmax4(f32x4 a, f32x4 b) {
  f32x4 r;
  #pragma unroll
  for (int i = 0; i < 4; ++i) r[i] = fmaxf(a[i], b[i]);
  return r;
}

static __device__ __forceinline__ f32x4 vexp2_4(f32x4 a) {
  f32x4 r;
  #pragma unroll
  for (int i = 0; i < 4; ++i) r[i] = fexp2(a[i]);
  return r;
}

static __device__ __forceinline__ void gload_lds16(const void* g, void* l) {
  __builtin_amdgcn_global_load_lds(
      (const __attribute__((address_space(1))) void*)g,
      (__attribute__((address_space(3))) void*)l, 16, 0, 0);
}

struct FT {
  const _Float16* P;  // row-side points [B,2048,64]
  const _Float16* Q;  // reduce-side points [B,2048,64]
};
struct MT {
  const float* psq;  // |p|^2 on output rows
  const float* oldf; // averaging input (nullptr = none)
  float* out;        // potential output [B,2048]
  const float* lwn;  // log-weights for NEXT round's hq (Q-side of consumer)
  const float* q2n;  // |q|^2 for NEXT round's hq
  float* hqn;        // hq slice of the consumer task
};

// ---------------- prep kernels ----------------

__global__ __launch_bounds__(256) void norm_weights_k(
    const float* __restrict__ w, float* __restrict__ aout,
    float* __restrict__ logout, int n) {
  int b = blockIdx.x;
  const float* wb = w + (size_t)b * n;
  __shared__ float red[256];
  float s = 0.f;
  for (int i = threadIdx.x; i < n; i += 256) s += wb[i];
  red[threadIdx.x] = s;
  __syncthreads();
  for (int st = 128; st > 0; st >>= 1) {
    if (threadIdx.x < st) red[threadIdx.x] += red[threadIdx.x + st];
    __syncthreads();
  }
  float mass = red[0];
  if (mass == 0.f) mass = 1.f;
  float inv = 1.f / mass;
  for (int i = threadIdx.x; i < n; i += 256) {
    float av = wb[i] * inv;
    aout[(size_t)b * n + i] = av;
    logout[(size_t)b * n + i] = logf(av);
  }
}

// squared norm of each D=64 row + fp16 conversion: one wave per row
__global__ __launch_bounds__(256) void sqnorm_cvt_k(
    const float* __restrict__ X, float* __restrict__ sq,
    _Float16* __restrict__ Xh, int rows) {
  int row = blockIdx.x * 4 + (threadIdx.x >> 6);
  int lane = threadIdx.x & 63;
  if (row >= rows) return;
  float v = X[(size_t)row * DIM + lane];
  Xh[(size_t)row * DIM + lane] = (_Float16)v;
  float s = v * v;
  #pragma unroll
  for (int off = 32; off > 0; off >>= 1) s += __shfl_xor(s, off);
  if (lane == 0) sq[row] = s;
}

// hq init (no potential): hq[t][b][m] = lw*log2e - 0.5*q2*ie2
__global__ __launch_bounds__(256) void init_hq_k(
    const float* __restrict__ la, const float* __restrict__ lb,
    const float* __restrict__ x2, const float* __restrict__ y2,
    float* __restrict__ hq, float ie2) {
  int task = blockIdx.z;
  int idx = blockIdx.x * 256 + threadIdx.x;  // over BB*NPTS
  const float* lw = (task == 1 || task == 2) ? la : lb;
  const float* q2 = (task == 1 || task == 2) ? x2 : y2;
  hq[(size_t)task * BB * NPTS + idx] =
      fmaf(lw[idx], LOG2E, -0.5f * q2[idx] * ie2);
}

// ---------------- fused cost+softmin (2 row-groups, amortized LSE) ---------
// Partial over one 512-col quarter: (M,S) per row with
//   v[r,m] = hq[m] + dot(P_r,Q_m)*ie2  (f16 MFMA 16x16x32, fp32 acc)
// Block = 4 waves x 32 P-rows (2 row-groups of 16, SHARING each staged
// B-fragment -> LDS-read bytes per entry halved vs 1 row-group).
// Cols swept in 64-col LDS chunks, double-buffered via global_load_lds,
// counted vmcnt (never 0 in loop), raw s_barriers. hq from precomputed
// global, staged to 2KB LDS. LSE: UNCONDITIONAL amortized rescale per
// 32-col group (R10 scheme). launch_bounds (256,6): VGPR cap ~85 —
// R12's (256,8)=64-cap spilled (74MB FETCH / 98MB WRITE scratch traffic);
// this is the same kernel with the cap lifted. LDS 18KB -> 6 blocks/CU.
__global__ __launch_bounds__(256, 6) void fused_softmin_k(
    FT t0, FT t1, FT t2, FT t3, const float* __restrict__ hqG,
    float* __restrict__ pmx, float* __restrict__ psm, float ie2) {
  __shared__ float hql[QC];                          // 2 KB
  __shared__ __align__(16) _Float16 qb[2][CK * DIM]; // 2 x 8 KB
  FT T = (blockIdx.z == 0) ? t0
       : (blockIdx.z == 1) ? t1
       : (blockIdx.z == 2) ? t2 : t3;
  const int rowg = blockIdx.x >> 2, qtr = blockIdx.x & 3;
  const int b = blockIdx.y, task = blockIdx.z;
  const int tid = threadIdx.x;

  // stage hq slice for this col-quarter (precomputed on global)
  {
    const float* hqp = hqG + ((size_t)task * BB + b) * NPTS + qtr * QC;
    #pragma unroll
    for (int i = 0; i < QC / 256; ++i)
      hql[i * 256 + tid] = hqp[i * 256 + tid];
  }

  const int lane = tid & 63, wave = tid >> 6;
  const _Float16* Qb = T.Q + ((size_t)b * NPTS + qtr * QC) * DIM;

  // stage chunk -> qb[buf]: linear LDS dest, inverse-swizzled global source
  // (rule #21). granule gid holds Q[m0+gid/8][8 halfs of k-granule
  // (gid%8)^((gid/8)&7)]. 2 global_load_lds per wave per chunk.
  auto stage = [&](int buf, int chunk) {
    int m0 = chunk * CK;
    #pragma unroll
    for (int r = 0; r < 2; ++r) {
      int gbase = r * 256 + wave * 64;
      int gid = gbase + lane;
      int row = gid >> 3;
      int kg = (gid & 7) ^ (row & 7);
      const _Float16* src = Qb + (size_t)(m0 + row) * DIM + kg * 8;
      _Float16* dst = &qb[buf][(size_t)gbase * 8];  // wave-uniform base
      gload_lds16(src, dst);
    }
  };

  const int fr = lane & 15;        // MFMA row/col index within fragment
  const int g0 = lane >> 4;        // k-granule group (0..3)
  const int r0 = rowg * BROWS + wave * 32;
  const _Float16* Pb = T.P + ((size_t)b * NPTS + r0) * DIM;
  f16x8 a00 = *(const f16x8*)(Pb + fr * DIM + g0 * 8);
  f16x8 a01 = *(const f16x8*)(Pb + fr * DIM + g0 * 8 + 32);
  f16x8 a10 = *(const f16x8*)(Pb + (16 + fr) * DIM + g0 * 8);
  f16x8 a11 = *(const f16x8*)(Pb + (16 + fr) * DIM + g0 * 8 + 32);

  f32x4 M0 = {-3.0e38f, -3.0e38f, -3.0e38f, -3.0e38f};
  f32x4 M1 = M0;
  f32x4 S0 = {0.f, 0.f, 0.f, 0.f};
  f32x4 S1 = S0;

  auto compute = [&](int cur, int mbase) {  // mbase local to the quarter
    const char* qbase = (const char*)&qb[cur][0];
    #pragma unroll
    for (int sh = 0; sh < 2; ++sh) {
      f32x4 acc00, acc01, acc10, acc11;  // static names (rule #20)
      float hs0, hs1;
      {
        int row = (sh * 2) * 16 + fr;
        int byte0 = row * 128 + ((g0 ^ (row & 7)) << 4);
        int byte1 = row * 128 + (((g0 + 4) ^ (row & 7)) << 4);
        f16x8 b0 = *(const f16x8*)(qbase + byte0);
        f16x8 b1 = *(const f16x8*)(qbase + byte1);
        hs0 = hql[mbase + (sh * 2) * 16 + fr];
        f32x4 z = {0.f, 0.f, 0.f, 0.f};
        f32x4 u0 = __builtin_amdgcn_mfma_f32_16x16x32_f16(a00, b0, z, 0, 0, 0);
        acc00 = __builtin_amdgcn_mfma_f32_16x16x32_f16(a01, b1, u0, 0, 0, 0);
        f32x4 u1 = __builtin_amdgcn_mfma_f32_16x16x32_f16(a10, b0, z, 0, 0, 0);
        acc10 = __builtin_amdgcn_mfma_f32_16x16x32_f16(a11, b1, u1, 0, 0, 0);
      }
      {
        int row = (sh * 2 + 1) * 16 + fr;
        int byte0 = row * 128 + ((g0 ^ (row & 7)) << 4);
        int byte1 = row * 128 + (((g0 + 4) ^ (row & 7)) << 4);
        f16x8 b0 = *(const f16x8*)(qbase + byte0);
        f16x8 b1 = *(const f16x8*)(qbase + byte1);
        hs1 = hql[mbase + (sh * 2 + 1) * 16 + fr];
        f32x4 z = {0.f, 0.f, 0.f, 0.f};
        f32x4 u0 = __builtin_amdgcn_mfma_f32_16x16x32_f16(a00, b0, z, 0, 0, 0);
        acc01 = __builtin_amdgcn_mfma_f32_16x16x32_f16(a01, b1, u0, 0, 0, 0);
        f32x4 u1 = __builtin_amdgcn_mfma_f32_16x16x32_f16(a10, b0, z, 0, 0, 0);
        acc11 = __builtin_amdgcn_mfma_f32_16x16x32_f16(a11, b1, u1, 0, 0, 0);
      }
      // amortized LSE over this 32-col group, row-group 0
      {
        f32x4 v0 = acc00 * ie2 + hs0;
        f32x4 v1 = acc01 * ie2 + hs1;
        f32x4 cm = vmax4(M0, vmax4(v0, v1));
        S0 = S0 * vexp2_4(M0 - cm) + vexp2_4(v0 - cm) + vexp2_4(v1 - cm);
        M0 = cm;
      }
      // row-group 1
      {
        f32x4 v0 = acc10 * ie2 + hs0;
        f32x4 v1 = acc11 * ie2 + hs1;
        f32x4 cm = vmax4(M1, vmax4(v0, v1));
        S1 = S1 * vexp2_4(M1 - cm) + vexp2_4(v0 - cm) + vexp2_4(v1 - cm);
        M1 = cm;
      }
    }
  };

  stage(0, 0);
  __syncthreads();  // one full drain: hql visible + chunk-0 staged

  for (int c = 0; c < NC - 1; ++c) {
    int cur = c & 1;
    stage(cur ^ 1, c + 1);  // buffer consumed in iter c-1 (B2 certified)
    // wait my chunk-c loads (2 oldest); keep chunk-(c+1)'s 2 in flight
    asm volatile("s_waitcnt vmcnt(2)" ::: "memory");
    __builtin_amdgcn_sched_barrier(0);
    __builtin_amdgcn_s_barrier();  // B1: chunk c globally staged
    __builtin_amdgcn_sched_barrier(0);
    compute(cur, c * CK);
    __builtin_amdgcn_sched_barrier(0);
    __builtin_amdgcn_s_barrier();  // B2: all waves done reading qb[cur]
    __builtin_amdgcn_sched_barrier(0);
  }
  // peeled last chunk: drain remaining loads (only time vmcnt hits 0)
  asm volatile("s_waitcnt vmcnt(0)" ::: "memory");
  __builtin_amdgcn_sched_barrier(0);
  __builtin_amdgcn_s_barrier();
  __builtin_amdgcn_sched_barrier(0);
  compute((NC - 1) & 1, (NC - 1) * CK);

  // reduce (M,S) pairs over the 16 fr lanes (cols) of each row group
  #pragma unroll
  for (int off = 1; off < 16; off <<= 1) {
    #pragma unroll
    for (int q = 0; q < 4; ++q) {
      {
        float om = __shfl_xor(M0[q], off);
        float os = __shfl_xor(S0[q], off);
        float nm = fmaxf(M0[q], om);
        S0[q] = S0[q] * fexp2(M0[q] - nm) + os * fexp2(om - nm);
        M0[q] = nm;
      }
      {
        float om = __shfl_xor(M1[q], off);
        float os = __shfl_xor(S1[q], off);
        float nm = fmaxf(M1[q], om);
        S1[q] = S1[q] * fexp2(M1[q] - nm) + os * fexp2(om - nm);
        M1[q] = nm;
      }
    }
  }
  if (fr == 0) {
    #pragma unroll
    for (int q = 0; q < 4; ++q) {
      // layout [task][b][qtr][row]
      size_t pbase = (((size_t)task * BB + b) * 4 + qtr) * NPTS;
      int ra = r0 + g0 * 4 + q;
      pmx[pbase + ra] = M0[q];
      psm[pbase + ra] = S0[q];
      int rb = ra + 16;
      pmx[pbase + rb] = M1[q];
      psm[pbase + rb] = S1[q];
    }
  }
}

// ---------------- merge quarters + epilogue + next-round hq ----------------
__global__ __launch_bounds__(256) void merge_k(
    const float* __restrict__ pmx, const float* __restrict__ psm,
    MT m0, MT m1, MT m2, MT m3, float nel, float ie2n, int whq) {
  int task = blockIdx.z;
  MT M = (task == 0) ? m0 : (task == 1) ? m1 : (task == 2) ? m2 : m3;
  int idx = blockIdx.x * 256 + threadIdx.x;  // over BB*NPTS
  int b = idx >> 11;                          // NPTS = 2048
  int r = idx & 2047;
  size_t pb = (((size_t)task * BB + b) * 4) * NPTS + r;
  float ma[4], sa[4];
  #pragma unroll
  for (int k = 0; k < 4; ++k) {
    ma[k] = pmx[pb + (size_t)k * NPTS];
    sa[k] = psm[pb + (size_t)k * NPTS];
  }
  float nm = fmaxf(fmaxf(ma[0], ma[1]), fmaxf(ma[2], ma[3]));
  float ss = 0.f;
  #pragma unroll
  for (int k = 0; k < 4; ++k) ss += sa[k] * fexp2(ma[k] - nm);
  float f = nel * (__log2f(ss) + nm) + 0.5f * M.psq[idx];
  if (M.oldf) f = 0.5f * (M.oldf[idx] + f);
  M.out[idx] = f;
  if (whq) {
    float h = fmaf(f, ie2n, fmaf(M.lwn[idx], LOG2E, -0.5f * M.q2n[idx] * ie2n));
    M.hqn[idx] = h;
  }
}

// ---------------- loss epilogue (two-stage) ----------------
__global__ __launch_bounds__(256) void loss_part_k(
    const float* __restrict__ aW, const float* __restrict__ f_fin,
    const float* __restrict__ f_aa, const float* __restrict__ bW,
    const float* __restrict__ g_fin, const float* __restrict__ g_bb,
    float* __restrict__ part) {
  __shared__ float red[256];
  int i0 = blockIdx.x * 256 + threadIdx.x;
  float s = 0.f;
  for (int i = i0; i < BB * NPTS; i += 64 * 256)
    s += aW[i] * (f_fin[i] - f_aa[i]) + bW[i] * (g_fin[i] - g_bb[i]);
  red[threadIdx.x] = s;
  __syncthreads();
  for (int st = 128; st > 0; st >>= 1) {
    if (threadIdx.x < st) red[threadIdx.x] += red[threadIdx.x + st];
    __syncthreads();
  }
  if (threadIdx.x == 0) part[blockIdx.x] = red[0];
}

__global__ __launch_bounds__(64) void loss_fin_k(const float* __restrict__ part,
                                                 float* __restrict__ out) {
  float s = part[threadIdx.x];
  #pragma unroll
  for (int off = 32; off > 0; off >>= 1) s += __shfl_xor(s, off);
  if (threadIdx.x == 0) out[0] = s * (1.f / BB);
}

__global__ void write_val_k(float* out, float v) { out[0] = v; }

// ---------------- host ----------------

extern "C" void kernel_launch(void* const* d_in, const int* in_sizes, int n_in,
                              void* d_out, int out_size, void* d_ws,
                              size_t ws_size, hipStream_t stream) {
  (void)in_sizes; (void)n_in; (void)out_size;
  const float* X = (const float*)d_in[0];   // [B,N,D]
  const float* Y = (const float*)d_in[1];   // [B,M,D]
  const float* W1 = (const float*)d_in[2];  // [B,N]
  const float* W2 = (const float*)d_in[3];  // [B,M]
  float* out = (float*)d_out;

  char* base = (char*)d_ws;
  size_t off = 0;
  auto alloc_b = [&](size_t bytes) {
    void* r = base + off;
    off += (bytes + 255) & ~(size_t)255;
    return r;
  };
  const size_t nP = (size_t)BB * NPTS;
  _Float16* Xh = (_Float16*)alloc_b(nP * DIM * 2);
  _Float16* Yh = (_Float16*)alloc_b(nP * DIM * 2);
  float* x2 = (float*)alloc_b(nP * 4);
  float* y2 = (float*)alloc_b(nP * 4);
  float* aW = (float*)alloc_b(nP * 4);
  float* bW = (float*)alloc_b(nP * 4);
  float* la = (float*)alloc_b(nP * 4);
  float* lb = (float*)alloc_b(nP * 4);
  float* fba[2] = {(float*)alloc_b(nP * 4), (float*)alloc_b(nP * 4)};
  float* gab[2] = {(float*)alloc_b(nP * 4), (float*)alloc_b(nP * 4)};
  float* faa[2] = {(float*)alloc_b(nP * 4), (float*)alloc_b(nP * 4)};
  float* gbb[2] = {(float*)alloc_b(nP * 4), (float*)alloc_b(nP * 4)};
  float* hq = (float*)alloc_b(4 * nP * 4);
  float* pmx = (float*)alloc_b(4 * nP * 4 * 4);
  float* psm = (float*)alloc_b(4 * nP * 4 * 4);
  float* part = (float*)alloc_b(64 * 4);
  if (ws_size < off) {
    write_val_k<<<1, 1, 0, stream>>>(out, -(float)(ws_size >> 20));
    return;
  }

  // prep
  norm_weights_k<<<BB, 256, 0, stream>>>(W1, aW, la, NPTS);
  norm_weights_k<<<BB, 256, 0, stream>>>(W2, bW, lb, NPTS);
  sqnorm_cvt_k<<<BB * NPTS / 4, 256, 0, stream>>>(X, x2, Xh, BB * NPTS);
  sqnorm_cvt_k<<<BB * NPTS / 4, 256, 0, stream>>>(Y, y2, Yh, BB * NPTS);

  dim3 fg(64, BB, 4);        // (rowg*4+qtr, b, task)
  dim3 mg(BB * NPTS / 256, 1, 4);

  FT t0{Xh, Yh}, t1{Yh, Xh}, t2{Xh, Xh}, t3{Yh, Yh};
  float* hq0 = hq;                 // task0 slice (f_ba: pot=gab)
  float* hq1 = hq + 1 * nP;        // task1 (g_ab: pot=fba)
  float* hq2 = hq + 2 * nP;        // task2 (f_aa: pot=faa)
  float* hq3 = hq + 3 * nP;        // task3 (g_bb: pot=gbb)

  auto fused = [&](float eps) {
    fused_softmin_k<<<fg, 256, 0, stream>>>(t0, t1, t2, t3, hq, pmx, psm,
                                            LOG2E / eps);
  };
  // merge for all 4 tasks; out-task t feeds hq of consumer: t0->hq1, t1->hq0,
  // t2->hq2, t3->hq3 (lw/q2 of the consumer's Q side).
  auto merge = [&](float eps, float ie2n, int whq, const float* oF,
                   float* nF, const float* oG, float* nG, const float* oA,
                   float* nA, const float* oB, float* nB) {
    float nel = -eps * LN2;
    MT M0{x2, oF, nF, la, x2, hq1};
    MT M1{y2, oG, nG, lb, y2, hq0};
    MT M2{x2, oA, nA, la, x2, hq2};
    MT M3{y2, oB, nB, lb, y2, hq3};
    merge_k<<<mg, 256, 0, stream>>>(pmx, psm, M0, M1, M2, M3, nel, ie2n, whq);
  };

  // hq for the init round (no potential)
  init_hq_k<<<mg, 256, 0, stream>>>(la, lb, x2, y2, hq, LOG2E / EPS_H[0]);

  // init round at eps0 (no averaging); next round is loop it=0 at eps0
  fused(EPS_H[0]);
  merge(EPS_H[0], LOG2E / EPS_H[0], 1, nullptr, fba[0], nullptr, gab[0],
        nullptr, faa[0], nullptr, gbb[0]);

  // annealing loop: averaged updates, double-buffered
  int cur = 0;
  for (int it = 0; it < 9; ++it) {
    int nxt = cur ^ 1;
    float epsn = EPS_H[it < 8 ? it + 1 : 8];  // it=8 feeds final extrapolation
    fused(EPS_H[it]);
    merge(EPS_H[it], LOG2E / epsn, 1, fba[cur], fba[nxt], gab[cur], gab[nxt],
          faa[cur], faa[nxt], gbb[cur], gbb[nxt]);
    cur = nxt;
  }

  // final extrapolation at eps target (no averaging, no hq write)
  {
    int nxt = cur ^ 1;
    fused(EPS_H[8]);
    merge(EPS_H[8], 0.f, 0, nullptr, fba[nxt], nullptr, gab[nxt], nullptr,
          faa[nxt], nullptr, gbb[nxt]);
    loss_part_k<<<64, 256, 0, stream>>>(aW, fba[nxt], faa[nxt], bW, gab[nxt],
                                        gbb[nxt], part);
    loss_fin_k<<<1, 64, 0, stream>>>(part, out);
  }
}

// Round 15
// 435.129 us; speedup vs baseline: 2.2380x; 1.0953x over previous
//
#include <hip/hip_runtime.h>
#include <cstdint>
#include <cstddef>

// Problem constants (B,N,M,D fixed by the reference setup_inputs)
#define BB 8
#define NPTS 2048
#define DIM 64
#define CK 64            // Q cols staged per chunk
#define QC 512           // cols per block (col-split by 4)
#define NC (QC / CK)     // 8 chunks
#define BROWS 128        // P rows per block (4 waves x 32 rows)

typedef _Float16 f16x8 __attribute__((ext_vector_type(8)));
typedef float f32x4 __attribute__((ext_vector_type(4)));

// eps schedule: DIAMETER^2 * 0.25^k down to blur^2 = 0.0025 (9 entries)
static const float EPS_H[9] = {100.0f, 25.0f, 6.25f, 1.5625f, 0.390625f,
                               0.09765625f, 0.0244140625f, 0.006103515625f,
                               0.0025f};
#define LOG2E 1.4426950408889634f
#define LN2 0.6931471805599453f

#if __has_builtin(__builtin_amdgcn_exp2f)
static __device__ __forceinline__ float fexp2(float x) {
  return __builtin_amdgcn_exp2f(x);
}
#else
static __device__ __forceinline__ float fexp2(float x) {
  float r;
  asm("v_exp_f32 %0, %1" : "=v"(r) : "v"(x));
  return r;
}
#endif

static __device__ __forceinline__ f32x4 vmax4(f32x4 a, f32x4 b) {
  f32x4 r;
  #pragma unroll
  for (int i = 0; i < 4; ++i) r[i] = fmaxf(a[i], b[i]);
  return r;
}

static __device__ __forceinline__ f32x4 vexp2_4(f32x4 a) {
  f32x4 r;
  #pragma unroll
  for (int i = 0; i < 4; ++i) r[i] = fexp2(a[i]);
  return r;
}

static __device__ __forceinline__ void gload_lds16(const void* g, void* l) {
  __builtin_amdgcn_global_load_lds(
      (const __attribute__((address_space(1))) void*)g,
      (__attribute__((address_space(3))) void*)l, 16, 0, 0);
}

struct FT {
  const _Float16* P;  // row-side points [B,2048,64]
  const _Float16* Q;  // reduce-side points [B,2048,64]
};
struct MT {
  const float* psq;  // |p|^2 on output rows
  const float* oldf; // averaging input (nullptr = none)
  float* out;        // potential output [B,2048]
  const float* lwn;  // log-weights for NEXT round's hq (Q-side of consumer)
  const float* q2n;  // |q|^2 for NEXT round's hq
  float* hqn;        // hq slice of the consumer task
};

// ---------------- prep kernels ----------------

__global__ __launch_bounds__(256) void norm_weights_k(
    const float* __restrict__ w, float* __restrict__ aout,
    float* __restrict__ logout, int n) {
  int b = blockIdx.x;
  const float* wb = w + (size_t)b * n;
  __shared__ float red[256];
  float s = 0.f;
  for (int i = threadIdx.x; i < n; i += 256) s += wb[i];
  red[threadIdx.x] = s;
  __syncthreads();
  for (int st = 128; st > 0; st >>= 1) {
    if (threadIdx.x < st) red[threadIdx.x] += red[threadIdx.x + st];
    __syncthreads();
  }
  float mass = red[0];
  if (mass == 0.f) mass = 1.f;
  float inv = 1.f / mass;
  for (int i = threadIdx.x; i < n; i += 256) {
    float av = wb[i] * inv;
    aout[(size_t)b * n + i] = av;
    logout[(size_t)b * n + i] = logf(av);
  }
}

// squared norm of each D=64 row + fp16 conversion: one wave per row
__global__ __launch_bounds__(256) void sqnorm_cvt_k(
    const float* __restrict__ X, float* __restrict__ sq,
    _Float16* __restrict__ Xh, int rows) {
  int row = blockIdx.x * 4 + (threadIdx.x >> 6);
  int lane = threadIdx.x & 63;
  if (row >= rows) return;
  float v = X[(size_t)row * DIM + lane];
  Xh[(size_t)row * DIM + lane] = (_Float16)v;
  float s = v * v;
  #pragma unroll
  for (int off = 32; off > 0; off >>= 1) s += __shfl_xor(s, off);
  if (lane == 0) sq[row] = s;
}

// hq init (no potential): hq[t][b][m] = lw*log2e - 0.5*q2*ie2
__global__ __launch_bounds__(256) void init_hq_k(
    const float* __restrict__ la, const float* __restrict__ lb,
    const float* __restrict__ x2, const float* __restrict__ y2,
    float* __restrict__ hq, float ie2) {
  int task = blockIdx.z;
  int idx = blockIdx.x * 256 + threadIdx.x;  // over BB*NPTS
  const float* lw = (task == 1 || task == 2) ? la : lb;
  const float* q2 = (task == 1 || task == 2) ? x2 : y2;
  hq[(size_t)task * BB * NPTS + idx] =
      fmaf(lw[idx], LOG2E, -0.5f * q2[idx] * ie2);
}

// ---------------- fused cost+softmin (2 row-groups) ----------
// Partial over one 512-col quarter: (M,S) per row with
//   v[r,m] = hq[m] + dot(P_r,Q_m)*ie2  (f16 MFMA 16x16x32, fp32 acc)
// Block = 4 waves x 32 P-rows (2 row-groups of 16, SHARING each staged
// B-fragment). Cols in 64-col LDS chunks, double-buffered global_load_lds,
// counted vmcnt (never 0 in loop), raw s_barriers. hq from precomputed
// global, staged to 2KB LDS.
// NM=1 (eps >= 6.25): |v| <= ~70 log2 units -> S += exp2(v) with M==0 is
// overflow/underflow-safe. Drops vmax tree + rescale exps + max shuffles
// (~45% fewer issue slots; the kernel is issue-port-bound).
// NM=0: UNCONDITIONAL amortized rescale per 32-col group (R10 scheme).
// launch_bounds (256,6): VGPR cap ~85, spill-proof (R12/R14 lesson).
template <int NM>
__global__ __launch_bounds__(256, 6) void fused_softmin_k(
    FT t0, FT t1, FT t2, FT t3, const float* __restrict__ hqG,
    float* __restrict__ pmx, float* __restrict__ psm, float ie2) {
  __shared__ float hql[QC];                          // 2 KB
  __shared__ __align__(16) _Float16 qb[2][CK * DIM]; // 2 x 8 KB
  FT T = (blockIdx.z == 0) ? t0
       : (blockIdx.z == 1) ? t1
       : (blockIdx.z == 2) ? t2 : t3;
  const int rowg = blockIdx.x >> 2, qtr = blockIdx.x & 3;
  const int b = blockIdx.y, task = blockIdx.z;
  const int tid = threadIdx.x;

  // stage hq slice for this col-quarter (precomputed on global)
  {
    const float* hqp = hqG + ((size_t)task * BB + b) * NPTS + qtr * QC;
    #pragma unroll
    for (int i = 0; i < QC / 256; ++i)
      hql[i * 256 + tid] = hqp[i * 256 + tid];
  }

  const int lane = tid & 63, wave = tid >> 6;
  const _Float16* Qb = T.Q + ((size_t)b * NPTS + qtr * QC) * DIM;

  // stage chunk -> qb[buf]: linear LDS dest, inverse-swizzled global source
  // (rule #21). granule gid holds Q[m0+gid/8][8 halfs of k-granule
  // (gid%8)^((gid/8)&7)]. 2 global_load_lds per wave per chunk.
  auto stage = [&](int buf, int chunk) {
    int m0 = chunk * CK;
    #pragma unroll
    for (int r = 0; r < 2; ++r) {
      int gbase = r * 256 + wave * 64;
      int gid = gbase + lane;
      int row = gid >> 3;
      int kg = (gid & 7) ^ (row & 7);
      const _Float16* src = Qb + (size_t)(m0 + row) * DIM + kg * 8;
      _Float16* dst = &qb[buf][(size_t)gbase * 8];  // wave-uniform base
      gload_lds16(src, dst);
    }
  };

  const int fr = lane & 15;        // MFMA row/col index within fragment
  const int g0 = lane >> 4;        // k-granule group (0..3)
  const int r0 = rowg * BROWS + wave * 32;
  const _Float16* Pb = T.P + ((size_t)b * NPTS + r0) * DIM;
  f16x8 a00 = *(const f16x8*)(Pb + fr * DIM + g0 * 8);
  f16x8 a01 = *(const f16x8*)(Pb + fr * DIM + g0 * 8 + 32);
  f16x8 a10 = *(const f16x8*)(Pb + (16 + fr) * DIM + g0 * 8);
  f16x8 a11 = *(const f16x8*)(Pb + (16 + fr) * DIM + g0 * 8 + 32);

  f32x4 M0 = NM ? f32x4{0.f, 0.f, 0.f, 0.f}
               : f32x4{-3.0e38f, -3.0e38f, -3.0e38f, -3.0e38f};
  f32x4 M1 = M0;
  f32x4 S0 = {0.f, 0.f, 0.f, 0.f};
  f32x4 S1 = S0;

  auto compute = [&](int cur, int mbase) {  // mbase local to the quarter
    const char* qbase = (const char*)&qb[cur][0];
    #pragma unroll
    for (int sh = 0; sh < 2; ++sh) {
      f32x4 acc00, acc01, acc10, acc11;  // static names (rule #20)
      float hs0, hs1;
      {
        int row = (sh * 2) * 16 + fr;
        int byte0 = row * 128 + ((g0 ^ (row & 7)) << 4);
        int byte1 = row * 128 + (((g0 + 4) ^ (row & 7)) << 4);
        f16x8 b0 = *(const f16x8*)(qbase + byte0);
        f16x8 b1 = *(const f16x8*)(qbase + byte1);
        hs0 = hql[mbase + (sh * 2) * 16 + fr];
        f32x4 z = {0.f, 0.f, 0.f, 0.f};
        f32x4 u0 = __builtin_amdgcn_mfma_f32_16x16x32_f16(a00, b0, z, 0, 0, 0);
        acc00 = __builtin_amdgcn_mfma_f32_16x16x32_f16(a01, b1, u0, 0, 0, 0);
        f32x4 u1 = __builtin_amdgcn_mfma_f32_16x16x32_f16(a10, b0, z, 0, 0, 0);
        acc10 = __builtin_amdgcn_mfma_f32_16x16x32_f16(a11, b1, u1, 0, 0, 0);
      }
      {
        int row = (sh * 2 + 1) * 16 + fr;
        int byte0 = row * 128 + ((g0 ^ (row & 7)) << 4);
        int byte1 = row * 128 + (((g0 + 4) ^ (row & 7)) << 4);
        f16x8 b0 = *(const f16x8*)(qbase + byte0);
        f16x8 b1 = *(const f16x8*)(qbase + byte1);
        hs1 = hql[mbase + (sh * 2 + 1) * 16 + fr];
        f32x4 z = {0.f, 0.f, 0.f, 0.f};
        f32x4 u0 = __builtin_amdgcn_mfma_f32_16x16x32_f16(a00, b0, z, 0, 0, 0);
        acc01 = __builtin_amdgcn_mfma_f32_16x16x32_f16(a01, b1, u0, 0, 0, 0);
        f32x4 u1 = __builtin_amdgcn_mfma_f32_16x16x32_f16(a10, b0, z, 0, 0, 0);
        acc11 = __builtin_amdgcn_mfma_f32_16x16x32_f16(a11, b1, u1, 0, 0, 0);
      }
      if (NM) {
        // eps >= 6.25: fixed M = 0, plain exp2 accumulation (no max machinery)
        S0 += vexp2_4(acc00 * ie2 + hs0) + vexp2_4(acc01 * ie2 + hs1);
        S1 += vexp2_4(acc10 * ie2 + hs0) + vexp2_4(acc11 * ie2 + hs1);
      } else {
        // amortized LSE over this 32-col group, row-group 0
        {
          f32x4 v0 = acc00 * ie2 + hs0;
          f32x4 v1 = acc01 * ie2 + hs1;
          f32x4 cm = vmax4(M0, vmax4(v0, v1));
          S0 = S0 * vexp2_4(M0 - cm) + vexp2_4(v0 - cm) + vexp2_4(v1 - cm);
          M0 = cm;
        }
        // row-group 1
        {
          f32x4 v0 = acc10 * ie2 + hs0;
          f32x4 v1 = acc11 * ie2 + hs1;
          f32x4 cm = vmax4(M1, vmax4(v0, v1));
          S1 = S1 * vexp2_4(M1 - cm) + vexp2_4(v0 - cm) + vexp2_4(v1 - cm);
          M1 = cm;
        }
      }
    }
  };

  stage(0, 0);
  __syncthreads();  // one full drain: hql visible + chunk-0 staged

  for (int c = 0; c < NC - 1; ++c) {
    int cur = c & 1;
    stage(cur ^ 1, c + 1);  // buffer consumed in iter c-1 (B2 certified)
    // wait my chunk-c loads (2 oldest); keep chunk-(c+1)'s 2 in flight
    asm volatile("s_waitcnt vmcnt(2)" ::: "memory");
    __builtin_amdgcn_sched_barrier(0);
    __builtin_amdgcn_s_barrier();  // B1: chunk c globally staged
    __builtin_amdgcn_sched_barrier(0);
    compute(cur, c * CK);
    __builtin_amdgcn_sched_barrier(0);
    __builtin_amdgcn_s_barrier();  // B2: all waves done reading qb[cur]
    __builtin_amdgcn_sched_barrier(0);
  }
  // peeled last chunk: drain remaining loads (only time vmcnt hits 0)
  asm volatile("s_waitcnt vmcnt(0)" ::: "memory");
  __builtin_amdgcn_sched_barrier(0);
  __builtin_amdgcn_s_barrier();
  __builtin_amdgcn_sched_barrier(0);
  compute((NC - 1) & 1, (NC - 1) * CK);

  // reduce over the 16 fr lanes (cols) of each row group
  #pragma unroll
  for (int off = 1; off < 16; off <<= 1) {
    #pragma unroll
    for (int q = 0; q < 4; ++q) {
      if (NM) {
        S0[q] += __shfl_xor(S0[q], off);
        S1[q] += __shfl_xor(S1[q], off);
      } else {
        {
          float om = __shfl_xor(M0[q], off);
          float os = __shfl_xor(S0[q], off);
          float nm = fmaxf(M0[q], om);
          S0[q] = S0[q] * fexp2(M0[q] - nm) + os * fexp2(om - nm);
          M0[q] = nm;
        }
        {
          float om = __shfl_xor(M1[q], off);
          float os = __shfl_xor(S1[q], off);
          float nm = fmaxf(M1[q], om);
          S1[q] = S1[q] * fexp2(M1[q] - nm) + os * fexp2(om - nm);
          M1[q] = nm;
        }
      }
    }
  }
  if (fr == 0) {
    #pragma unroll
    for (int q = 0; q < 4; ++q) {
      // layout [task][b][qtr][row]
      size_t pbase = (((size_t)task * BB + b) * 4 + qtr) * NPTS;
      int ra = r0 + g0 * 4 + q;
      pmx[pbase + ra] = NM ? 0.f : M0[q];
      psm[pbase + ra] = S0[q];
      int rb = ra + 16;
      pmx[pbase + rb] = NM ? 0.f : M1[q];
      psm[pbase + rb] = S1[q];
    }
  }
}

// ---------------- merge quarters + epilogue + next-round hq ----------------
__global__ __launch_bounds__(256) void merge_k(
    const float* __restrict__ pmx, const float* __restrict__ psm,
    MT m0, MT m1, MT m2, MT m3, float nel, float ie2n, int whq, int nomax) {
  int task = blockIdx.z;
  MT M = (task == 0) ? m0 : (task == 1) ? m1 : (task == 2) ? m2 : m3;
  int idx = blockIdx.x * 256 + threadIdx.x;  // over BB*NPTS
  int b = idx >> 11;                          // NPTS = 2048
  int r = idx & 2047;
  size_t pb = (((size_t)task * BB + b) * 4) * NPTS + r;
  float nm, ss;
  if (nomax) {
    nm = 0.f;
    ss = psm[pb] + psm[pb + (size_t)NPTS] + psm[pb + (size_t)2 * NPTS] +
         psm[pb + (size_t)3 * NPTS];
  } else {
    float ma[4], sa[4];
    #pragma unroll
    for (int k = 0; k < 4; ++k) {
      ma[k] = pmx[pb + (size_t)k * NPTS];
      sa[k] = psm[pb + (size_t)k * NPTS];
    }
    nm = fmaxf(fmaxf(ma[0], ma[1]), fmaxf(ma[2], ma[3]));
    ss = 0.f;
    #pragma unroll
    for (int k = 0; k < 4; ++k) ss += sa[k] * fexp2(ma[k] - nm);
  }
  float f = nel * (__log2f(ss) + nm) + 0.5f * M.psq[idx];
  if (M.oldf) f = 0.5f * (M.oldf[idx] + f);
  M.out[idx] = f;
  if (whq) {
    float h = fmaf(f, ie2n, fmaf(M.lwn[idx], LOG2E, -0.5f * M.q2n[idx] * ie2n));
    M.hqn[idx] = h;
  }
}

// ---------------- loss epilogue (two-stage) ----------------
__global__ __launch_bounds__(256) void loss_part_k(
    const float* __restrict__ aW, const float* __restrict__ f_fin,
    const float* __restrict__ f_aa, const float* __restrict__ bW,
    const float* __restrict__ g_fin, const float* __restrict__ g_bb,
    float* __restrict__ part) {
  __shared__ float red[256];
  int i0 = blockIdx.x * 256 + threadIdx.x;
  float s = 0.f;
  for (int i = i0; i < BB * NPTS; i += 64 * 256)
    s += aW[i] * (f_fin[i] - f_aa[i]) + bW[i] * (g_fin[i] - g_bb[i]);
  red[threadIdx.x] = s;
  __syncthreads();
  for (int st = 128; st > 0; st >>= 1) {
    if (threadIdx.x < st) red[threadIdx.x] += red[threadIdx.x + st];
    __syncthreads();
  }
  if (threadIdx.x == 0) part[blockIdx.x] = red[0];
}

__global__ __launch_bounds__(64) void loss_fin_k(const float* __restrict__ part,
                                                 float* __restrict__ out) {
  float s = part[threadIdx.x];
  #pragma unroll
  for (int off = 32; off > 0; off >>= 1) s += __shfl_xor(s, off);
  if (threadIdx.x == 0) out[0] = s * (1.f / BB);
}

__global__ void write_val_k(float* out, float v) { out[0] = v; }

// ---------------- host ----------------

extern "C" void kernel_launch(void* const* d_in, const int* in_sizes, int n_in,
                              void* d_out, int out_size, void* d_ws,
                              size_t ws_size, hipStream_t stream) {
  (void)in_sizes; (void)n_in; (void)out_size;
  const float* X = (const float*)d_in[0];   // [B,N,D]
  const float* Y = (const float*)d_in[1];   // [B,M,D]
  const float* W1 = (const float*)d_in[2];  // [B,N]
  const float* W2 = (const float*)d_in[3];  // [B,M]
  float* out = (float*)d_out;

  char* base = (char*)d_ws;
  size_t off = 0;
  auto alloc_b = [&](size_t bytes) {
    void* r = base + off;
    off += (bytes + 255) & ~(size_t)255;
    return r;
  };
  const size_t nP = (size_t)BB * NPTS;
  _Float16* Xh = (_Float16*)alloc_b(nP * DIM * 2);
  _Float16* Yh = (_Float16*)alloc_b(nP * DIM * 2);
  float* x2 = (float*)alloc_b(nP * 4);
  float* y2 = (float*)alloc_b(nP * 4);
  float* aW = (float*)alloc_b(nP * 4);
  float* bW = (float*)alloc_b(nP * 4);
  float* la = (float*)alloc_b(nP * 4);
  float* lb = (float*)alloc_b(nP * 4);
  float* fba[2] = {(float*)alloc_b(nP * 4), (float*)alloc_b(nP * 4)};
  float* gab[2] = {(float*)alloc_b(nP * 4), (float*)alloc_b(nP * 4)};
  float* faa[2] = {(float*)alloc_b(nP * 4), (float*)alloc_b(nP * 4)};
  float* gbb[2] = {(float*)alloc_b(nP * 4), (float*)alloc_b(nP * 4)};
  float* hq = (float*)alloc_b(4 * nP * 4);
  float* pmx = (float*)alloc_b(4 * nP * 4 * 4);
  float* psm = (float*)alloc_b(4 * nP * 4 * 4);
  float* part = (float*)alloc_b(64 * 4);
  if (ws_size < off) {
    write_val_k<<<1, 1, 0, stream>>>(out, -(float)(ws_size >> 20));
    return;
  }

  // prep
  norm_weights_k<<<BB, 256, 0, stream>>>(W1, aW, la, NPTS);
  norm_weights_k<<<BB, 256, 0, stream>>>(W2, bW, lb, NPTS);
  sqnorm_cvt_k<<<BB * NPTS / 4, 256, 0, stream>>>(X, x2, Xh, BB * NPTS);
  sqnorm_cvt_k<<<BB * NPTS / 4, 256, 0, stream>>>(Y, y2, Yh, BB * NPTS);

  dim3 fg(64, BB, 4);        // (rowg*4+qtr, b, task)
  dim3 mg(BB * NPTS / 256, 1, 4);

  FT t0{Xh, Yh}, t1{Yh, Xh}, t2{Xh, Xh}, t3{Yh, Yh};
  float* hq0 = hq;                 // task0 slice (f_ba: pot=gab)
  float* hq1 = hq + 1 * nP;        // task1 (g_ab: pot=fba)
  float* hq2 = hq + 2 * nP;        // task2 (f_aa: pot=faa)
  float* hq3 = hq + 3 * nP;        // task3 (g_bb: pot=gbb)

  // NOMAX safe iff eps >= 6.25: |v| <= ~70 log2 units (see kernel comment)
  auto fused = [&](float eps) {
    if (eps >= 6.0f)
      fused_softmin_k<1><<<fg, 256, 0, stream>>>(t0, t1, t2, t3, hq, pmx, psm,
                                                 LOG2E / eps);
    else
      fused_softmin_k<0><<<fg, 256, 0, stream>>>(t0, t1, t2, t3, hq, pmx, psm,
                                                 LOG2E / eps);
  };
  // merge for all 4 tasks; out-task t feeds hq of consumer: t0->hq1, t1->hq0,
  // t2->hq2, t3->hq3 (lw/q2 of the consumer's Q side).
  auto merge = [&](float eps, float ie2n, int whq, const float* oF,
                   float* nF, const float* oG, float* nG, const float* oA,
                   float* nA, const float* oB, float* nB) {
    float nel = -eps * LN2;
    int nomax = (eps >= 6.0f) ? 1 : 0;
    MT M0{x2, oF, nF, la, x2, hq1};
    MT M1{y2, oG, nG, lb, y2, hq0};
    MT M2{x2, oA, nA, la, x2, hq2};
    MT M3{y2, oB, nB, lb, y2, hq3};
    merge_k<<<mg, 256, 0, stream>>>(pmx, psm, M0, M1, M2, M3, nel, ie2n, whq,
                                    nomax);
  };

  // hq for the init round (no potential)
  init_hq_k<<<mg, 256, 0, stream>>>(la, lb, x2, y2, hq, LOG2E / EPS_H[0]);

  // init round at eps0 (no averaging); next round is loop it=0 at eps0
  fused(EPS_H[0]);
  merge(EPS_H[0], LOG2E / EPS_H[0], 1, nullptr, fba[0], nullptr, gab[0],
        nullptr, faa[0], nullptr, gbb[0]);

  // annealing loop: averaged updates, double-buffered
  int cur = 0;
  for (int it = 0; it < 9; ++it) {
    int nxt = cur ^ 1;
    float epsn = EPS_H[it < 8 ? it + 1 : 8];  // it=8 feeds final extrapolation
    fused(EPS_H[it]);
    merge(EPS_H[it], LOG2E / epsn, 1, fba[cur], fba[nxt], gab[cur], gab[nxt],
          faa[cur], faa[nxt], gbb[cur], gbb[nxt]);
    cur = nxt;
  }

  // final extrapolation at eps target (no averaging, no hq write)
  {
    int nxt = cur ^ 1;
    fused(EPS_H[8]);
    merge(EPS_H[8], 0.f, 0, nullptr, fba[nxt], nullptr, gab[nxt], nullptr,
          faa[nxt], nullptr, gbb[nxt]);
    loss_part_k<<<64, 256, 0, stream>>>(aW, fba[nxt], faa[nxt], bW, gab[nxt],
                                        gbb[nxt], part);
    loss_fin_k<<<1, 64, 0, stream>>>(part, out);
  }
}